// Round 24
// baseline (562.503 us; speedup 1.0000x reference)
//
#include <hip/hip_runtime.h>
#include <hip/hip_bf16.h>
#include <math.h>

typedef __bf16 bf16x8 __attribute__((ext_vector_type(8)));
typedef float f32x4 __attribute__((ext_vector_type(4)));
typedef unsigned short u16;
typedef unsigned int u32;
typedef u16 u16x4 __attribute__((ext_vector_type(4)));
typedef u16 u16x8 __attribute__((ext_vector_type(8)));

#define TOKENS 16384
#define MROWS  65536

__device__ __forceinline__ u16 f2bf(float f) {
  union { __hip_bfloat16 h; u16 u; } c;
  c.h = __float2bfloat16(f);
  return c.u;
}
__device__ __forceinline__ float bf2f(u16 u) {
  union { u16 u; __hip_bfloat16 h; } c;
  c.u = u;
  return __bfloat162float(c.h);
}
// sigmoid-form gelu (validated r6-r23, absmax 6.1e-5)
__device__ __forceinline__ float gelu_f(float u) {
  float y2 = u * fmaf(0.07135481283f, u * u, 1.595769122f);
  float e = __expf(-y2);
  return u / (1.f + e);
}
// async global->LDS, 16B per lane; LDS dest is wave-uniform base + lane*16
__device__ __forceinline__ void gload16(const void* g, void* l) {
  __builtin_amdgcn_global_load_lds(
      (const __attribute__((address_space(1))) void*)g,
      (__attribute__((address_space(3))) void*)l, 16, 0, 0);
}

// ---------------- prep kernels ----------------
__global__ void kprep_G(const float* __restrict__ Wq, const float* __restrict__ Wk,
                        u16* __restrict__ Gbf) {
  int id = blockIdx.x * 256 + threadIdx.x;  // 16384
  int c = id >> 7, c2 = id & 127;
  const float4* a = (const float4*)(Wq + (size_t)c * 512);
  const float4* b = (const float4*)(Wk + (size_t)c2 * 512);
  float s = 0.f;
#pragma unroll 8
  for (int i = 0; i < 128; ++i) {
    float4 xa = a[i], yb = b[i];
    s += xa.x * yb.x + xa.y * yb.y + xa.z * yb.z + xa.w * yb.w;
  }
  Gbf[id] = f2bf(s * 0.044194173824159216f);
}

__global__ void kprep_Wvp(const float* __restrict__ Wv, const float* __restrict__ Wp,
                          u16* __restrict__ WvpT) {
  int id = blockIdx.x * 256 + threadIdx.x;  // 65536 : e*128+c
  int e = id >> 7, c = id & 127;
  float s = 0.f;
#pragma unroll 4
  for (int d = 0; d < 512; ++d) s += Wv[(size_t)c * 512 + d] * Wp[(size_t)d * 512 + e];
  WvpT[id] = f2bf(s);
}

// W1T[f][e] = bf16(W1[e][f]) via 64x64 LDS tile: coalesced reads AND writes.
__global__ __launch_bounds__(256) void kprep_W1T(const float* __restrict__ W1,
                                                 u16* __restrict__ W1T) {
  __shared__ u16 Lt[64][72];  // [e_local][f_local]
  int tid = threadIdx.x;
  int bf = blockIdx.x, be = blockIdx.y;
#pragma unroll
  for (int rnd = 0; rnd < 4; ++rnd) {
    int r = rnd * 16 + (tid >> 4);          // e_local
    int f4 = (tid & 15) * 4;                // f_local
    float4 v = *(const float4*)(W1 + (size_t)(be * 64 + r) * 2048 + bf * 64 + f4);
    Lt[r][f4] = f2bf(v.x); Lt[r][f4 + 1] = f2bf(v.y);
    Lt[r][f4 + 2] = f2bf(v.z); Lt[r][f4 + 3] = f2bf(v.w);
  }
  __syncthreads();
  int fl = tid >> 2, eg = (tid & 3) * 16;
  u16x8 o0, o1;
#pragma unroll
  for (int q = 0; q < 8; ++q) { o0[q] = Lt[eg + q][fl]; o1[q] = Lt[eg + 8 + q][fl]; }
  u16* dst = W1T + (size_t)(bf * 64 + fl) * 512 + be * 64 + eg;
  *(u16x8*)dst = o0;
  *(u16x8*)(dst + 8) = o1;
}

// W2T[e][fst] = bf16(W2[f_true][e]), H-column permutation per 128-block (validated).
__global__ __launch_bounds__(256) void kprep_W2T(const float* __restrict__ W2,
                                                 u16* __restrict__ W2T) {
  __shared__ u16 Lt[64][72];  // [f_local][e_local]
  int tid = threadIdx.x;
  int bf = blockIdx.x, be = blockIdx.y;
#pragma unroll
  for (int rnd = 0; rnd < 4; ++rnd) {
    int r = rnd * 16 + (tid >> 4);          // f_local
    int e4 = (tid & 15) * 4;                // e_local
    float4 v = *(const float4*)(W2 + (size_t)(bf * 64 + r) * 512 + be * 64 + e4);
    Lt[r][e4] = f2bf(v.x); Lt[r][e4 + 1] = f2bf(v.y);
    Lt[r][e4 + 2] = f2bf(v.z); Lt[r][e4 + 3] = f2bf(v.w);
  }
  __syncthreads();
  int aa = bf & 1, fb = bf >> 1;
  int el = tid >> 2, g = tid & 3;
  u16x8 o0, o1;
#pragma unroll
  for (int q = 0; q < 8; ++q) {
    int fs0 = g * 16 + q, fs1 = g * 16 + 8 + q;
    o0[q] = Lt[(fs0 & 3) * 16 + ((fs0 >> 2) & 15)][el];
    o1[q] = Lt[(fs1 & 3) * 16 + ((fs1 >> 2) & 15)][el];
  }
  u16* dst = W2T + (size_t)(be * 64 + el) * 2048 + fb * 128 + aa * 64 + g * 16;
  *(u16x8*)dst = o0;
  *(u16x8*)(dst + 8) = o1;
}

// ======== fused token-attention + projection + residual + LN1 -> X1 ========
// Block = 32 tokens (128 rows), 1024 threads (16 waves), 128KB LDS (1 block/CU).
// Phase 1: sequential per-token (r23, spill-light) with VECTORIZED Sw reads:
// float4 LDS broadcasts cut c-loop LDS issues 640->256 per token.
__global__ __launch_bounds__(1024)
void kfused(const float* __restrict__ x,
            const u16* __restrict__ Gbf,
            const u16* __restrict__ WvpT,
            const float* __restrict__ bp,
            const float* __restrict__ g1,
            const float* __restrict__ bln1,
            u16* __restrict__ X1) {
  __shared__ __align__(16) char smem[131072];
  int tid = threadIdx.x;
  int lane = tid & 63, wid = tid >> 6;
  int m0 = blockIdx.x * 128;      // output rows
  int tok0 = blockIdx.x * 32;     // tokens
  // ---- stage G (32KB) and x (64KB) ----
#pragma unroll
  for (int it = 0; it < 2; ++it)
    gload16(Gbf + (size_t)(it * 1024 + tid) * 8, smem + (it * 1024 + tid) * 16);
  {
    const float* xsrc = x + (size_t)tok0 * 512;
#pragma unroll
    for (int it = 0; it < 4; ++it)
      gload16(xsrc + (it * 1024 + tid) * 4, smem + 32768 + (it * 1024 + tid) * 16);
  }
  __syncthreads();
  float* Xs = (float*)(smem + 32768);
  const u32* Grow = (const u32*)smem;
  char* Zbase = smem + 98304;
  // ---- phase 1: token attention, 2 tokens sequential; per-row softmax ----
  {
    int c2 = lane * 2;
    for (int tt = 0; tt < 2; ++tt) {
      int tl = wid * 2 + tt;
      const float* Sw = Xs + tl * 512;
      const float4* Sw4 = (const float4*)Sw;
      float a[4][2] = {{0.f,0.f},{0.f,0.f},{0.f,0.f},{0.f,0.f}};
      for (int c4 = 0; c4 < 32; ++c4) {
        float4 f0 = Sw4[c4];
        float4 f1 = Sw4[32 + c4];
        float4 f2 = Sw4[64 + c4];
        float4 f3 = Sw4[96 + c4];
        const u32* gbase = Grow + c4 * 256 + lane;
#pragma unroll
        for (int k = 0; k < 4; ++k) {
          u32 g2 = gbase[k * 64];
          float glo = __uint_as_float(g2 << 16);
          float ghi = __uint_as_float(g2 & 0xFFFF0000u);
          float s0 = (k == 0) ? f0.x : (k == 1) ? f0.y : (k == 2) ? f0.z : f0.w;
          float s1 = (k == 0) ? f1.x : (k == 1) ? f1.y : (k == 2) ? f1.z : f1.w;
          float s2 = (k == 0) ? f2.x : (k == 1) ? f2.y : (k == 2) ? f2.z : f2.w;
          float s3 = (k == 0) ? f3.x : (k == 1) ? f3.y : (k == 2) ? f3.z : f3.w;
          a[0][0] += s0 * glo; a[0][1] += s0 * ghi;
          a[1][0] += s1 * glo; a[1][1] += s1 * ghi;
          a[2][0] += s2 * glo; a[2][1] += s2 * ghi;
          a[3][0] += s3 * glo; a[3][1] += s3 * ghi;
        }
      }
#pragma unroll
      for (int i = 0; i < 4; ++i) {
        float w4[4];
#pragma unroll
        for (int j = 0; j < 4; ++j)
          w4[j] = a[i][0] * Sw[j * 128 + c2] + a[i][1] * Sw[j * 128 + c2 + 1];
#pragma unroll
        for (int off = 1; off < 64; off <<= 1)
#pragma unroll
          for (int k = 0; k < 4; ++k) w4[k] += __shfl_xor(w4[k], off);
        float m = w4[0];
        for (int j = 1; j <= i; ++j) m = fmaxf(m, w4[j]);
        float p4[4];
        float s = 0.f;
        for (int j = 0; j <= i; ++j) { p4[j] = __expf(w4[j] - m); s += p4[j]; }
        float inv = 1.f / s;
        for (int j = 0; j <= i; ++j) p4[j] *= inv;
        for (int j = i + 1; j < 4; ++j) p4[j] = 0.f;
        float z0 = 0.f, z1 = 0.f;
#pragma unroll
        for (int j = 0; j < 4; ++j) {
          z0 += p4[j] * Sw[j * 128 + c2];
          z1 += p4[j] * Sw[j * 128 + c2 + 1];
        }
        int row = tl * 4 + i;
        int byte = (row * 256 + lane * 4) ^ ((row & 7) << 4);
        *(u32*)(Zbase + byte) = (u32)f2bf(z0) | ((u32)f2bf(z1) << 16);
      }
    }
  }
  __syncthreads();  // Z tile complete
  // ---- phase 2: GEMM (Z[128][128] @ WvpT) ----
  int wm = wid >> 2, wnq = wid & 3;
  int lane_lo = lane & 15, lane_hi = lane >> 4;
  f32x4 acc[2][8];
#pragma unroll
  for (int mi = 0; mi < 2; ++mi)
#pragma unroll
    for (int ni = 0; ni < 8; ++ni) acc[mi][ni] = (f32x4){0.f, 0.f, 0.f, 0.f};
#pragma unroll
  for (int ks = 0; ks < 4; ++ks) {
    bf16x8 af[2];
#pragma unroll
    for (int mi = 0; mi < 2; ++mi) {
      int row = mi * 64 + wm * 16 + lane_lo;
      int byte = (row * 256 + (ks * 32 + lane_hi * 8) * 2) ^ ((row & 7) << 4);
      af[mi] = *(const bf16x8*)(Zbase + byte);
    }
#pragma unroll
    for (int ni = 0; ni < 8; ++ni) {
      int n = wnq * 128 + ni * 16 + lane_lo;
      bf16x8 bfr = *(const bf16x8*)(WvpT + (size_t)n * 128 + ks * 32 + lane_hi * 8);
#pragma unroll
      for (int mi = 0; mi < 2; ++mi)
        acc[mi][ni] = __builtin_amdgcn_mfma_f32_16x16x32_bf16(af[mi], bfr, acc[mi][ni], 0, 0, 0);
    }
  }
  __syncthreads();  // all Z reads done -> stats alias Z region
  float* rsum = (float*)Zbase;
  float* rsq  = (float*)(Zbase + 8192);
  float* mus  = (float*)(Zbase + 16384);
  float* rss  = (float*)(Zbase + 17408);
  float bpv[8], g1v[8], blv[8];
#pragma unroll
  for (int ni = 0; ni < 8; ++ni) {
    int col = wnq * 128 + ni * 16 + lane_lo;
    bpv[ni] = bp[col]; g1v[ni] = g1[col]; blv[ni] = bln1[col];
  }
#pragma unroll
  for (int mi = 0; mi < 2; ++mi) {
#pragma unroll
    for (int j = 0; j < 4; ++j) {
      int rl = mi * 64 + wm * 16 + lane_hi * 4 + j;
      int tl = mi * 16 + wm * 4 + lane_hi;
      float s = 0.f, q = 0.f;
#pragma unroll
      for (int ni = 0; ni < 8; ++ni) {
        int col = wnq * 128 + ni * 16 + lane_lo;
        float val = acc[mi][ni][j] + bpv[ni] + Xs[tl * 512 + col];
        acc[mi][ni][j] = val;
        s += val; q += val * val;
      }
#pragma unroll
      for (int off = 1; off < 16; off <<= 1) { s += __shfl_xor(s, off); q += __shfl_xor(q, off); }
      if (lane_lo == 0) { rsum[rl * 4 + wnq] = s; rsq[rl * 4 + wnq] = q; }
    }
  }
  __syncthreads();
  if (tid < 128) {
    float s = rsum[tid * 4] + rsum[tid * 4 + 1] + rsum[tid * 4 + 2] + rsum[tid * 4 + 3];
    float q = rsq[tid * 4] + rsq[tid * 4 + 1] + rsq[tid * 4 + 2] + rsq[tid * 4 + 3];
    float mu = s * (1.f / 512.f);
    float var = q * (1.f / 512.f) - mu * mu;
    mus[tid] = mu;
    rss[tid] = rsqrtf(var + 512.0f);
  }
  __syncthreads();
  // out-stage in two 64-row halves over [0,64K) (G and x dead)
  u16* AO = (u16*)smem;
#pragma unroll
  for (int half = 0; half < 2; ++half) {
    int mi = half;
#pragma unroll
    for (int j = 0; j < 4; ++j) {
      int rl = mi * 64 + wm * 16 + lane_hi * 4 + j;
      float mu = mus[rl], rs = rss[rl];
      int rlh = rl - half * 64;
#pragma unroll
      for (int ni = 0; ni < 8; ++ni) {
        int col = wnq * 128 + ni * 16 + lane_lo;
        AO[rlh * 512 + col] = f2bf((acc[mi][ni][j] - mu) * rs * g1v[ni] + blv[ni]);
      }
    }
    __syncthreads();
    {
      bf16x8* dst = (bf16x8*)(X1 + (size_t)(m0 + half * 64) * 512);
      const bf16x8* s8 = (const bf16x8*)AO;
#pragma unroll
      for (int it = 0; it < 4; ++it) dst[it * 1024 + tid] = s8[it * 1024 + tid];
    }
    __syncthreads();
  }
}

// ===== 256x128 single-buffered GEMM core (r14-proven for kff1; 3 blocks/CU) =====
template<int KDIM>
__device__ __forceinline__ void gemm256(const u16* __restrict__ Ap,
                                        const u16* __restrict__ Bp,
                                        u16* Ab, u16* Bb,
                                        int wid, int lane, f32x4 acc[4][4]) {
  char* AbC = (char*)Ab;
  char* BbC = (char*)Bb;
  const int lane_lo = lane & 15, lane_hi = lane >> 4;
  const int wm = wid >> 1, wn = wid & 1;
  const int rl8 = lane >> 3, u8 = lane & 7;
  for (int k0 = 0; k0 < KDIM; k0 += 64) {
#pragma unroll
    for (int i = 0; i < 4; ++i) {
      int row = wid * 32 + i * 8 + rl8;
      int usw = u8 ^ (row & 7);
      gload16(Ap + (size_t)row * KDIM + k0 + usw * 8, AbC + wid * 4096 + i * 1024);
    }
#pragma unroll
    for (int i = 0; i < 2; ++i) {
      int row = wid * 16 + i * 8 + rl8;
      int usw = u8 ^ (row & 7);
      gload16(Bp + (size_t)row * KDIM + k0 + usw * 8, BbC + wid * 2048 + i * 1024);
    }
    __syncthreads();
#pragma unroll
    for (int ks = 0; ks < 2; ++ks) {
      bf16x8 av[4], bv[4];
#pragma unroll
      for (int mi = 0; mi < 4; ++mi) {
        int row = wm * 64 + mi * 16 + lane_lo;
        int usw = (ks * 4 + lane_hi) ^ (row & 7);
        av[mi] = *(const bf16x8*)(AbC + row * 128 + usw * 16);
      }
#pragma unroll
      for (int ni = 0; ni < 4; ++ni) {
        int row = wn * 64 + ni * 16 + lane_lo;
        int usw = (ks * 4 + lane_hi) ^ (row & 7);
        bv[ni] = *(const bf16x8*)(BbC + row * 128 + usw * 16);
      }
#pragma unroll
      for (int mi = 0; mi < 4; ++mi)
#pragma unroll
        for (int ni = 0; ni < 4; ++ni)
          acc[mi][ni] = __builtin_amdgcn_mfma_f32_16x16x32_bf16(av[mi], bv[ni], acc[mi][ni], 0, 0, 0);
    }
    __syncthreads();
  }
}

// ======== 2-phase double-buffered 128^2 core (r8/r14-proven for kff2) ========
template<int KDIM>
__device__ __forceinline__ void gemm_core_db(const u16* __restrict__ Ap,
                                             const u16* __restrict__ Bp,
                                             u16* AbBase, u16* BbBase,
                                             int wid, int lane, f32x4 acc[4][4]) {
  const int lane_lo = lane & 15, lane_hi = lane >> 4;
  const int wm = wid >> 1, wn = wid & 1;
  const int rl8 = lane >> 3, u8 = lane & 7;

  auto stage = [&](int buf, int k0) {
    char* AbC = (char*)AbBase + buf * 16384;
    char* BbC = (char*)BbBase + buf * 16384;
#pragma unroll
    for (int i = 0; i < 4; ++i) {
      int row = wid * 32 + i * 8 + rl8;
      int usw = u8 ^ (row & 7);
      size_t goff = (size_t)row * KDIM + k0 + usw * 8;
      gload16(Ap + goff, AbC + wid * 4096 + i * 1024);
      gload16(Bp + goff, BbC + wid * 4096 + i * 1024);
    }
  };
  auto compute = [&](int buf) {
    char* AbC = (char*)AbBase + buf * 16384;
    char* BbC = (char*)BbBase + buf * 16384;
#pragma unroll
    for (int ks = 0; ks < 2; ++ks) {
      bf16x8 av[4], bv[4];
#pragma unroll
      for (int mi = 0; mi < 4; ++mi) {
        int row = wm * 64 + mi * 16 + lane_lo;
        int usw = (ks * 4 + lane_hi) ^ (row & 7);
        av[mi] = *(const bf16x8*)(AbC + row * 128 + usw * 16);
      }
#pragma unroll
      for (int ni = 0; ni < 4; ++ni) {
        int row = wn * 64 + ni * 16 + lane_lo;
        int usw = (ks * 4 + lane_hi) ^ (row & 7);
        bv[ni] = *(const bf16x8*)(BbC + row * 128 + usw * 16);
      }
#pragma unroll
      for (int mi = 0; mi < 4; ++mi)
#pragma unroll
        for (int ni = 0; ni < 4; ++ni)
          acc[mi][ni] = __builtin_amdgcn_mfma_f32_16x16x32_bf16(av[mi], bv[ni], acc[mi][ni], 0, 0, 0);
    }
  };

  stage(0, 0);
  asm volatile("s_waitcnt vmcnt(0)" ::: "memory");
  __builtin_amdgcn_s_barrier();
  __builtin_amdgcn_sched_barrier(0);
  int cur = 0;
  for (int k0 = 64; k0 < KDIM; k0 += 64) {
    stage(cur ^ 1, k0);
    compute(cur);
    asm volatile("s_waitcnt vmcnt(0)" ::: "memory");
    __builtin_amdgcn_s_barrier();
    __builtin_amdgcn_sched_barrier(0);
    cur ^= 1;
  }
  compute(cur);
}

// FF1: H = gelu(X1 @ W1 + b1), K=512, N=2048 (16 n-blocks); 256x128 tile.
__global__ __launch_bounds__(512) void kff1(const u16* __restrict__ X1s,
                                            const u16* __restrict__ W1T,
                                            const float* __restrict__ b1v,
                                            u16* __restrict__ H) {
  __shared__ __align__(16) u16 Ab[16384];  // 32KB [256][64]
  __shared__ __align__(16) u16 Bb[8192];   // 16KB [128][64]
  int tid = threadIdx.x, lane = tid & 63, wid = tid >> 6;
  int lane_lo = lane & 15, lane_hi = lane >> 4;
  int wm = wid >> 1, wn = wid & 1;
  int nwg = gridDim.x, bid = blockIdx.x;
  int m256 = nwg >> 4;
  int xcd = bid & 7, idx = bid >> 3;
  int mb = xcd * (m256 >> 3) + (idx >> 4);
  int nb = idx & 15;
  const u16* Ap = X1s + (size_t)mb * 256 * 512;
  const u16* Bp = W1T + (size_t)nb * 128 * 512;
  f32x4 acc[4][4];
#pragma unroll
  for (int mi = 0; mi < 4; ++mi)
#pragma unroll
    for (int ni = 0; ni < 4; ++ni) acc[mi][ni] = (f32x4){0.f, 0.f, 0.f, 0.f};
  gemm256<512>(Ap, Bp, Ab, Bb, wid, lane, acc);
  float bvals[4];
#pragma unroll
  for (int ni = 0; ni < 4; ++ni) bvals[ni] = b1v[nb * 128 + wn * 64 + ni * 16 + lane_lo];
  int colb = nb * 128 + (wn * 16 + lane_lo) * 4;
#pragma unroll
  for (int mi = 0; mi < 4; ++mi)
#pragma unroll
    for (int j = 0; j < 4; ++j) {
      int rl = wm * 64 + mi * 16 + lane_hi * 4 + j;
      u16x4 pk;
#pragma unroll
      for (int ni = 0; ni < 4; ++ni)
        pk[ni] = f2bf(gelu_f(acc[mi][ni][j] + bvals[ni]));
      *(u16x4*)(H + ((size_t)mb * 256 + rl) * 2048 + colb) = pk;
    }
}

// FF2: y = H @ W2 + b2 + X1, bf16 IN-PLACE over X1; dbuf 128^2 core.
__global__ __launch_bounds__(256) void kff2(const u16* __restrict__ H,
                                            const u16* __restrict__ W2T,
                                            const float* __restrict__ b2v,
                                            u16* __restrict__ X1y) {
  __shared__ __align__(16) u16 Ab[16384];
  __shared__ __align__(16) u16 Bb[16384];
  int tid = threadIdx.x, lane = tid & 63, wid = tid >> 6;
  int nwg = gridDim.x, bid = blockIdx.x;
  int m128 = nwg >> 2;
  int xcd = bid & 7, idx = bid >> 3;
  int mb = xcd * (m128 >> 3) + (idx >> 2);
  int nb = idx & 3;
  const u16* Ap = H + (size_t)mb * 128 * 2048;
  const u16* Bp = W2T + (size_t)nb * 128 * 2048;
  f32x4 acc[4][4];
#pragma unroll
  for (int mi = 0; mi < 4; ++mi)
#pragma unroll
    for (int ni = 0; ni < 4; ++ni) acc[mi][ni] = (f32x4){0.f, 0.f, 0.f, 0.f};
  gemm_core_db<2048>(Ap, Bp, Ab, Bb, wid, lane, acc);
  int lane_lo = lane & 15, lane_hi = lane >> 4;
  int wm = wid >> 1, wn = wid & 1;
#pragma unroll
  for (int mi = 0; mi < 4; ++mi)
#pragma unroll
    for (int j = 0; j < 4; ++j) {
      int rl = wm * 64 + mi * 16 + lane_hi * 4 + j;
      size_t row = (size_t)mb * 128 + rl;
      u16* xrow = X1y + row * 512 + nb * 128;
#pragma unroll
      for (int ni = 0; ni < 4; ++ni) {
        int col = wn * 64 + ni * 16 + lane_lo;
        float val = acc[mi][ni][j] + b2v[nb * 128 + col] + bf2f(xrow[col]);
        xrow[col] = f2bf(val);
      }
    }
}

// LN2: out = LN(y) where y is bf16 (in X1 buffer). One wave per row.
__global__ __launch_bounds__(512) void kln2(const u16* __restrict__ Y,
                                            const float* __restrict__ g2,
                                            const float* __restrict__ bb2,
                                            float* __restrict__ out) {
  int wid = threadIdx.x >> 6, lane = threadIdx.x & 63;
  size_t row = (size_t)blockIdx.x * 8 + wid;
  u16x8 v = *(const u16x8*)(Y + row * 512 + lane * 8);
  float f[8];
  float s = 0.f, q = 0.f;
#pragma unroll
  for (int k = 0; k < 8; ++k) {
    f[k] = bf2f(v[k]);
    s += f[k]; q += f[k] * f[k];
  }
#pragma unroll
  for (int off = 1; off < 64; off <<= 1) { s += __shfl_xor(s, off); q += __shfl_xor(q, off); }
  float mu = s * (1.f / 512.f);
  float rs = rsqrtf(q * (1.f / 512.f) - mu * mu + 512.0f);
  float4 ga = *(const float4*)(g2 + lane * 8);
  float4 gb = *(const float4*)(g2 + lane * 8 + 4);
  float4 ba = *(const float4*)(bb2 + lane * 8);
  float4 bb = *(const float4*)(bb2 + lane * 8 + 4);
  float4 o0, o1;
  o0.x = (f[0] - mu) * rs * ga.x + ba.x;
  o0.y = (f[1] - mu) * rs * ga.y + ba.y;
  o0.z = (f[2] - mu) * rs * ga.z + ba.z;
  o0.w = (f[3] - mu) * rs * ga.w + ba.w;
  o1.x = (f[4] - mu) * rs * gb.x + bb.x;
  o1.y = (f[5] - mu) * rs * gb.y + bb.y;
  o1.z = (f[6] - mu) * rs * gb.z + bb.z;
  o1.w = (f[7] - mu) * rs * gb.w + bb.w;
  float* orow = out + row * 512 + lane * 8;
  *(float4*)orow = o0;
  *(float4*)(orow + 4) = o1;
}

extern "C" void kernel_launch(void* const* d_in, const int* in_sizes, int n_in,
                              void* d_out, int out_size, void* d_ws, size_t ws_size,
                              hipStream_t stream) {
  const float* x   = (const float*)d_in[0];
  const float* Wq  = (const float*)d_in[1];
  const float* Wk  = (const float*)d_in[2];
  const float* Wv  = (const float*)d_in[3];
  const float* Wp  = (const float*)d_in[4];
  const float* bp  = (const float*)d_in[5];
  const float* W1  = (const float*)d_in[6];
  const float* b1  = (const float*)d_in[7];
  const float* W2  = (const float*)d_in[8];
  const float* b2  = (const float*)d_in[9];
  const float* g1  = (const float*)d_in[10];
  const float* bb1 = (const float*)d_in[11];
  const float* g2  = (const float*)d_in[12];
  const float* bb2 = (const float*)d_in[13];
  float* out = (float*)d_out;

  char* ws = (char*)d_ws;
  u16* Gbf  = (u16*)ws;                      // 32KB (region reserved 256KB)
  u16* WvpT = (u16*)(ws + (256 << 10));      // 128KB
  u16* W1T  = (u16*)(ws + (1 << 20));        // 2MB
  u16* W2T  = (u16*)(ws + (3 << 20));        // 2MB
  u16* X1   = (u16*)(ws + (21 << 20));       // 64MB (becomes y bf16 after kff2)
  u16* H    = (u16*)(ws + (85ull << 20));    // H slice region

  hipLaunchKernelGGL(kprep_G,   dim3(64),        dim3(256), 0, stream, Wq, Wk, Gbf);
  hipLaunchKernelGGL(kprep_Wvp, dim3(256),       dim3(256), 0, stream, Wv, Wp, WvpT);
  hipLaunchKernelGGL(kprep_W1T, dim3(32, 8),     dim3(256), 0, stream, W1, W1T);
  hipLaunchKernelGGL(kprep_W2T, dim3(32, 8),     dim3(256), 0, stream, W2, W2T);
  hipLaunchKernelGGL(kfused,    dim3(512),       dim3(1024), 0, stream, x, Gbf, WvpT,
                     bp, g1, bb1, X1);

  // S=2 preferred (H slice 128MB L3-resident, fewer launch tails); fallback smaller.
  const size_t hbase = 85ull << 20;
  int S = 64;
  for (int c = 2; c <= 64; c <<= 1) {
    if (hbase + (268435456ull / (size_t)c) <= ws_size) { S = c; break; }
  }
  int Ms = MROWS / S;
  for (int s = 0; s < S; ++s) {
    const u16* x1s = X1 + (size_t)s * Ms * 512;
    hipLaunchKernelGGL(kff1, dim3((Ms / 256) * 16), dim3(512), 0, stream, x1s, W1T, b1, H);
    hipLaunchKernelGGL(kff2, dim3((Ms / 128) * 4),  dim3(256), 0, stream, H, W2T, b2,
                       X1 + (size_t)s * Ms * 512);
  }
  hipLaunchKernelGGL(kln2, dim3(8192), dim3(512), 0, stream, X1, g2, bb2, out);
}

// Round 25
// 551.314 us; speedup vs baseline: 1.0203x; 1.0203x over previous
//
#include <hip/hip_runtime.h>
#include <hip/hip_bf16.h>
#include <math.h>

typedef __bf16 bf16x8 __attribute__((ext_vector_type(8)));
typedef float f32x4 __attribute__((ext_vector_type(4)));
typedef unsigned short u16;
typedef unsigned int u32;
typedef u16 u16x4 __attribute__((ext_vector_type(4)));
typedef u16 u16x8 __attribute__((ext_vector_type(8)));

#define TOKENS 16384
#define MROWS  65536

__device__ __forceinline__ u16 f2bf(float f) {
  union { __hip_bfloat16 h; u16 u; } c;
  c.h = __float2bfloat16(f);
  return c.u;
}
__device__ __forceinline__ float bf2f(u16 u) {
  union { u16 u; __hip_bfloat16 h; } c;
  c.u = u;
  return __bfloat162float(c.h);
}
// sigmoid-form gelu (validated r6-r24, absmax 6.1e-5)
__device__ __forceinline__ float gelu_f(float u) {
  float y2 = u * fmaf(0.07135481283f, u * u, 1.595769122f);
  float e = __expf(-y2);
  return u / (1.f + e);
}
// async global->LDS, 16B per lane; LDS dest is wave-uniform base + lane*16
__device__ __forceinline__ void gload16(const void* g, void* l) {
  __builtin_amdgcn_global_load_lds(
      (const __attribute__((address_space(1))) void*)g,
      (__attribute__((address_space(3))) void*)l, 16, 0, 0);
}

// ---------------- prep kernels ----------------
__global__ void kprep_G(const float* __restrict__ Wq, const float* __restrict__ Wk,
                        u16* __restrict__ Gbf) {
  int id = blockIdx.x * 256 + threadIdx.x;  // 16384
  int c = id >> 7, c2 = id & 127;
  const float4* a = (const float4*)(Wq + (size_t)c * 512);
  const float4* b = (const float4*)(Wk + (size_t)c2 * 512);
  float s = 0.f;
#pragma unroll 8
  for (int i = 0; i < 128; ++i) {
    float4 xa = a[i], yb = b[i];
    s += xa.x * yb.x + xa.y * yb.y + xa.z * yb.z + xa.w * yb.w;
  }
  Gbf[id] = f2bf(s * 0.044194173824159216f);
}

__global__ void kprep_Wvp(const float* __restrict__ Wv, const float* __restrict__ Wp,
                          u16* __restrict__ WvpT) {
  int id = blockIdx.x * 256 + threadIdx.x;  // 65536 : e*128+c
  int e = id >> 7, c = id & 127;
  float s = 0.f;
#pragma unroll 4
  for (int d = 0; d < 512; ++d) s += Wv[(size_t)c * 512 + d] * Wp[(size_t)d * 512 + e];
  WvpT[id] = f2bf(s);
}

// W1T[f][e] = bf16(W1[e][f]) via 64x64 LDS tile: coalesced reads AND writes.
__global__ __launch_bounds__(256) void kprep_W1T(const float* __restrict__ W1,
                                                 u16* __restrict__ W1T) {
  __shared__ u16 Lt[64][72];  // [e_local][f_local]
  int tid = threadIdx.x;
  int bf = blockIdx.x, be = blockIdx.y;
#pragma unroll
  for (int rnd = 0; rnd < 4; ++rnd) {
    int r = rnd * 16 + (tid >> 4);          // e_local
    int f4 = (tid & 15) * 4;                // f_local
    float4 v = *(const float4*)(W1 + (size_t)(be * 64 + r) * 2048 + bf * 64 + f4);
    Lt[r][f4] = f2bf(v.x); Lt[r][f4 + 1] = f2bf(v.y);
    Lt[r][f4 + 2] = f2bf(v.z); Lt[r][f4 + 3] = f2bf(v.w);
  }
  __syncthreads();
  int fl = tid >> 2, eg = (tid & 3) * 16;
  u16x8 o0, o1;
#pragma unroll
  for (int q = 0; q < 8; ++q) { o0[q] = Lt[eg + q][fl]; o1[q] = Lt[eg + 8 + q][fl]; }
  u16* dst = W1T + (size_t)(bf * 64 + fl) * 512 + be * 64 + eg;
  *(u16x8*)dst = o0;
  *(u16x8*)(dst + 8) = o1;
}

// W2T[e][fst] = bf16(W2[f_true][e]), H-column permutation per 128-block (validated).
__global__ __launch_bounds__(256) void kprep_W2T(const float* __restrict__ W2,
                                                 u16* __restrict__ W2T) {
  __shared__ u16 Lt[64][72];  // [f_local][e_local]
  int tid = threadIdx.x;
  int bf = blockIdx.x, be = blockIdx.y;
#pragma unroll
  for (int rnd = 0; rnd < 4; ++rnd) {
    int r = rnd * 16 + (tid >> 4);          // f_local
    int e4 = (tid & 15) * 4;                // e_local
    float4 v = *(const float4*)(W2 + (size_t)(bf * 64 + r) * 512 + be * 64 + e4);
    Lt[r][e4] = f2bf(v.x); Lt[r][e4 + 1] = f2bf(v.y);
    Lt[r][e4 + 2] = f2bf(v.z); Lt[r][e4 + 3] = f2bf(v.w);
  }
  __syncthreads();
  int aa = bf & 1, fb = bf >> 1;
  int el = tid >> 2, g = tid & 3;
  u16x8 o0, o1;
#pragma unroll
  for (int q = 0; q < 8; ++q) {
    int fs0 = g * 16 + q, fs1 = g * 16 + 8 + q;
    o0[q] = Lt[(fs0 & 3) * 16 + ((fs0 >> 2) & 15)][el];
    o1[q] = Lt[(fs1 & 3) * 16 + ((fs1 >> 2) & 15)][el];
  }
  u16* dst = W2T + (size_t)(be * 64 + el) * 2048 + fb * 128 + aa * 64 + g * 16;
  *(u16x8*)dst = o0;
  *(u16x8*)(dst + 8) = o1;
}

// ======== fused token-attention + projection + residual + LN1 -> X1 ========
// r21 configuration (best measured: 120.9us kernel / 551.3us total).
// Block = 32 tokens (128 rows), 1024 threads (16 waves), 128KB LDS (1 block/CU).
// Phase 1 interleaves the wave's 2 tokens in one c-loop (1 G-read serves both),
// then per-row w4 butterfly + softmax.
__global__ __launch_bounds__(1024)
void kfused(const float* __restrict__ x,
            const u16* __restrict__ Gbf,
            const u16* __restrict__ WvpT,
            const float* __restrict__ bp,
            const float* __restrict__ g1,
            const float* __restrict__ bln1,
            u16* __restrict__ X1) {
  __shared__ __align__(16) char smem[131072];
  int tid = threadIdx.x;
  int lane = tid & 63, wid = tid >> 6;
  int m0 = blockIdx.x * 128;      // output rows
  int tok0 = blockIdx.x * 32;     // tokens
  // ---- stage G (32KB) and x (64KB) ----
#pragma unroll
  for (int it = 0; it < 2; ++it)
    gload16(Gbf + (size_t)(it * 1024 + tid) * 8, smem + (it * 1024 + tid) * 16);
  {
    const float* xsrc = x + (size_t)tok0 * 512;
#pragma unroll
    for (int it = 0; it < 4; ++it)
      gload16(xsrc + (it * 1024 + tid) * 4, smem + 32768 + (it * 1024 + tid) * 16);
  }
  __syncthreads();
  float* Xs = (float*)(smem + 32768);
  const u32* Grow = (const u32*)smem;
  char* Zbase = smem + 98304;
  // ---- phase 1: token attention, 2 tokens interleaved; per-row softmax ----
  {
    const float* Sw0 = Xs + (wid * 2) * 512;
    const float* Sw1 = Sw0 + 512;
    float a0[4][2] = {{0.f,0.f},{0.f,0.f},{0.f,0.f},{0.f,0.f}};
    float a1[4][2] = {{0.f,0.f},{0.f,0.f},{0.f,0.f},{0.f,0.f}};
#pragma unroll 4
    for (int c = 0; c < 128; ++c) {
      u32 g2 = Grow[c * 64 + lane];
      float glo = __uint_as_float(g2 << 16);
      float ghi = __uint_as_float(g2 & 0xFFFF0000u);
#pragma unroll
      for (int i = 0; i < 4; ++i) {
        float sa = Sw0[i * 128 + c];
        float sb = Sw1[i * 128 + c];
        a0[i][0] += sa * glo; a0[i][1] += sa * ghi;
        a1[i][0] += sb * glo; a1[i][1] += sb * ghi;
      }
    }
    int c2 = lane * 2;
#pragma unroll
    for (int tt = 0; tt < 2; ++tt) {
      int tl = wid * 2 + tt;
      const float* Sw = tt ? Sw1 : Sw0;
      float (*a)[2] = tt ? a1 : a0;
#pragma unroll
      for (int i = 0; i < 4; ++i) {
        float w4[4];
#pragma unroll
        for (int j = 0; j < 4; ++j)
          w4[j] = a[i][0] * Sw[j * 128 + c2] + a[i][1] * Sw[j * 128 + c2 + 1];
#pragma unroll
        for (int off = 1; off < 64; off <<= 1)
#pragma unroll
          for (int k = 0; k < 4; ++k) w4[k] += __shfl_xor(w4[k], off);
        float m = w4[0];
        for (int j = 1; j <= i; ++j) m = fmaxf(m, w4[j]);
        float p4[4];
        float s = 0.f;
        for (int j = 0; j <= i; ++j) { p4[j] = __expf(w4[j] - m); s += p4[j]; }
        float inv = 1.f / s;
        for (int j = 0; j <= i; ++j) p4[j] *= inv;
        for (int j = i + 1; j < 4; ++j) p4[j] = 0.f;
        float z0 = 0.f, z1 = 0.f;
#pragma unroll
        for (int j = 0; j < 4; ++j) {
          z0 += p4[j] * Sw[j * 128 + c2];
          z1 += p4[j] * Sw[j * 128 + c2 + 1];
        }
        int row = tl * 4 + i;
        int byte = (row * 256 + lane * 4) ^ ((row & 7) << 4);
        *(u32*)(Zbase + byte) = (u32)f2bf(z0) | ((u32)f2bf(z1) << 16);
      }
    }
  }
  __syncthreads();  // Z tile complete
  // ---- phase 2: GEMM (Z[128][128] @ WvpT) ----
  int wm = wid >> 2, wnq = wid & 3;
  int lane_lo = lane & 15, lane_hi = lane >> 4;
  f32x4 acc[2][8];
#pragma unroll
  for (int mi = 0; mi < 2; ++mi)
#pragma unroll
    for (int ni = 0; ni < 8; ++ni) acc[mi][ni] = (f32x4){0.f, 0.f, 0.f, 0.f};
#pragma unroll
  for (int ks = 0; ks < 4; ++ks) {
    bf16x8 af[2];
#pragma unroll
    for (int mi = 0; mi < 2; ++mi) {
      int row = mi * 64 + wm * 16 + lane_lo;
      int byte = (row * 256 + (ks * 32 + lane_hi * 8) * 2) ^ ((row & 7) << 4);
      af[mi] = *(const bf16x8*)(Zbase + byte);
    }
#pragma unroll
    for (int ni = 0; ni < 8; ++ni) {
      int n = wnq * 128 + ni * 16 + lane_lo;
      bf16x8 bfr = *(const bf16x8*)(WvpT + (size_t)n * 128 + ks * 32 + lane_hi * 8);
#pragma unroll
      for (int mi = 0; mi < 2; ++mi)
        acc[mi][ni] = __builtin_amdgcn_mfma_f32_16x16x32_bf16(af[mi], bfr, acc[mi][ni], 0, 0, 0);
    }
  }
  __syncthreads();  // all Z reads done -> stats alias Z region
  float* rsum = (float*)Zbase;
  float* rsq  = (float*)(Zbase + 8192);
  float* mus  = (float*)(Zbase + 16384);
  float* rss  = (float*)(Zbase + 17408);
  float bpv[8], g1v[8], blv[8];
#pragma unroll
  for (int ni = 0; ni < 8; ++ni) {
    int col = wnq * 128 + ni * 16 + lane_lo;
    bpv[ni] = bp[col]; g1v[ni] = g1[col]; blv[ni] = bln1[col];
  }
#pragma unroll
  for (int mi = 0; mi < 2; ++mi) {
#pragma unroll
    for (int j = 0; j < 4; ++j) {
      int rl = mi * 64 + wm * 16 + lane_hi * 4 + j;
      int tl = mi * 16 + wm * 4 + lane_hi;
      float s = 0.f, q = 0.f;
#pragma unroll
      for (int ni = 0; ni < 8; ++ni) {
        int col = wnq * 128 + ni * 16 + lane_lo;
        float val = acc[mi][ni][j] + bpv[ni] + Xs[tl * 512 + col];
        acc[mi][ni][j] = val;
        s += val; q += val * val;
      }
#pragma unroll
      for (int off = 1; off < 16; off <<= 1) { s += __shfl_xor(s, off); q += __shfl_xor(q, off); }
      if (lane_lo == 0) { rsum[rl * 4 + wnq] = s; rsq[rl * 4 + wnq] = q; }
    }
  }
  __syncthreads();
  if (tid < 128) {
    float s = rsum[tid * 4] + rsum[tid * 4 + 1] + rsum[tid * 4 + 2] + rsum[tid * 4 + 3];
    float q = rsq[tid * 4] + rsq[tid * 4 + 1] + rsq[tid * 4 + 2] + rsq[tid * 4 + 3];
    float mu = s * (1.f / 512.f);
    float var = q * (1.f / 512.f) - mu * mu;
    mus[tid] = mu;
    rss[tid] = rsqrtf(var + 512.0f);
  }
  __syncthreads();
  // out-stage in two 64-row halves over [0,64K) (G and x dead)
  u16* AO = (u16*)smem;
#pragma unroll
  for (int half = 0; half < 2; ++half) {
    int mi = half;
#pragma unroll
    for (int j = 0; j < 4; ++j) {
      int rl = mi * 64 + wm * 16 + lane_hi * 4 + j;
      float mu = mus[rl], rs = rss[rl];
      int rlh = rl - half * 64;
#pragma unroll
      for (int ni = 0; ni < 8; ++ni) {
        int col = wnq * 128 + ni * 16 + lane_lo;
        AO[rlh * 512 + col] = f2bf((acc[mi][ni][j] - mu) * rs * g1v[ni] + blv[ni]);
      }
    }
    __syncthreads();
    {
      bf16x8* dst = (bf16x8*)(X1 + (size_t)(m0 + half * 64) * 512);
      const bf16x8* s8 = (const bf16x8*)AO;
#pragma unroll
      for (int it = 0; it < 4; ++it) dst[it * 1024 + tid] = s8[it * 1024 + tid];
    }
    __syncthreads();
  }
}

// ===== 256x128 single-buffered GEMM core (r14-proven for kff1; 3 blocks/CU) =====
template<int KDIM>
__device__ __forceinline__ void gemm256(const u16* __restrict__ Ap,
                                        const u16* __restrict__ Bp,
                                        u16* Ab, u16* Bb,
                                        int wid, int lane, f32x4 acc[4][4]) {
  char* AbC = (char*)Ab;
  char* BbC = (char*)Bb;
  const int lane_lo = lane & 15, lane_hi = lane >> 4;
  const int wm = wid >> 1, wn = wid & 1;
  const int rl8 = lane >> 3, u8 = lane & 7;
  for (int k0 = 0; k0 < KDIM; k0 += 64) {
#pragma unroll
    for (int i = 0; i < 4; ++i) {
      int row = wid * 32 + i * 8 + rl8;
      int usw = u8 ^ (row & 7);
      gload16(Ap + (size_t)row * KDIM + k0 + usw * 8, AbC + wid * 4096 + i * 1024);
    }
#pragma unroll
    for (int i = 0; i < 2; ++i) {
      int row = wid * 16 + i * 8 + rl8;
      int usw = u8 ^ (row & 7);
      gload16(Bp + (size_t)row * KDIM + k0 + usw * 8, BbC + wid * 2048 + i * 1024);
    }
    __syncthreads();
#pragma unroll
    for (int ks = 0; ks < 2; ++ks) {
      bf16x8 av[4], bv[4];
#pragma unroll
      for (int mi = 0; mi < 4; ++mi) {
        int row = wm * 64 + mi * 16 + lane_lo;
        int usw = (ks * 4 + lane_hi) ^ (row & 7);
        av[mi] = *(const bf16x8*)(AbC + row * 128 + usw * 16);
      }
#pragma unroll
      for (int ni = 0; ni < 4; ++ni) {
        int row = wn * 64 + ni * 16 + lane_lo;
        int usw = (ks * 4 + lane_hi) ^ (row & 7);
        bv[ni] = *(const bf16x8*)(BbC + row * 128 + usw * 16);
      }
#pragma unroll
      for (int mi = 0; mi < 4; ++mi)
#pragma unroll
        for (int ni = 0; ni < 4; ++ni)
          acc[mi][ni] = __builtin_amdgcn_mfma_f32_16x16x32_bf16(av[mi], bv[ni], acc[mi][ni], 0, 0, 0);
    }
    __syncthreads();
  }
}

// ======== 2-phase double-buffered 128^2 core (r8/r14-proven for kff2) ========
template<int KDIM>
__device__ __forceinline__ void gemm_core_db(const u16* __restrict__ Ap,
                                             const u16* __restrict__ Bp,
                                             u16* AbBase, u16* BbBase,
                                             int wid, int lane, f32x4 acc[4][4]) {
  const int lane_lo = lane & 15, lane_hi = lane >> 4;
  const int wm = wid >> 1, wn = wid & 1;
  const int rl8 = lane >> 3, u8 = lane & 7;

  auto stage = [&](int buf, int k0) {
    char* AbC = (char*)AbBase + buf * 16384;
    char* BbC = (char*)BbBase + buf * 16384;
#pragma unroll
    for (int i = 0; i < 4; ++i) {
      int row = wid * 32 + i * 8 + rl8;
      int usw = u8 ^ (row & 7);
      size_t goff = (size_t)row * KDIM + k0 + usw * 8;
      gload16(Ap + goff, AbC + wid * 4096 + i * 1024);
      gload16(Bp + goff, BbC + wid * 4096 + i * 1024);
    }
  };
  auto compute = [&](int buf) {
    char* AbC = (char*)AbBase + buf * 16384;
    char* BbC = (char*)BbBase + buf * 16384;
#pragma unroll
    for (int ks = 0; ks < 2; ++ks) {
      bf16x8 av[4], bv[4];
#pragma unroll
      for (int mi = 0; mi < 4; ++mi) {
        int row = wm * 64 + mi * 16 + lane_lo;
        int usw = (ks * 4 + lane_hi) ^ (row & 7);
        av[mi] = *(const bf16x8*)(AbC + row * 128 + usw * 16);
      }
#pragma unroll
      for (int ni = 0; ni < 4; ++ni) {
        int row = wn * 64 + ni * 16 + lane_lo;
        int usw = (ks * 4 + lane_hi) ^ (row & 7);
        bv[ni] = *(const bf16x8*)(BbC + row * 128 + usw * 16);
      }
#pragma unroll
      for (int mi = 0; mi < 4; ++mi)
#pragma unroll
        for (int ni = 0; ni < 4; ++ni)
          acc[mi][ni] = __builtin_amdgcn_mfma_f32_16x16x32_bf16(av[mi], bv[ni], acc[mi][ni], 0, 0, 0);
    }
  };

  stage(0, 0);
  asm volatile("s_waitcnt vmcnt(0)" ::: "memory");
  __builtin_amdgcn_s_barrier();
  __builtin_amdgcn_sched_barrier(0);
  int cur = 0;
  for (int k0 = 64; k0 < KDIM; k0 += 64) {
    stage(cur ^ 1, k0);
    compute(cur);
    asm volatile("s_waitcnt vmcnt(0)" ::: "memory");
    __builtin_amdgcn_s_barrier();
    __builtin_amdgcn_sched_barrier(0);
    cur ^= 1;
  }
  compute(cur);
}

// FF1: H = gelu(X1 @ W1 + b1), K=512, N=2048 (16 n-blocks); 256x128 tile.
__global__ __launch_bounds__(512) void kff1(const u16* __restrict__ X1s,
                                            const u16* __restrict__ W1T,
                                            const float* __restrict__ b1v,
                                            u16* __restrict__ H) {
  __shared__ __align__(16) u16 Ab[16384];  // 32KB [256][64]
  __shared__ __align__(16) u16 Bb[8192];   // 16KB [128][64]
  int tid = threadIdx.x, lane = tid & 63, wid = tid >> 6;
  int lane_lo = lane & 15, lane_hi = lane >> 4;
  int wm = wid >> 1, wn = wid & 1;
  int nwg = gridDim.x, bid = blockIdx.x;
  int m256 = nwg >> 4;
  int xcd = bid & 7, idx = bid >> 3;
  int mb = xcd * (m256 >> 3) + (idx >> 4);
  int nb = idx & 15;
  const u16* Ap = X1s + (size_t)mb * 256 * 512;
  const u16* Bp = W1T + (size_t)nb * 128 * 512;
  f32x4 acc[4][4];
#pragma unroll
  for (int mi = 0; mi < 4; ++mi)
#pragma unroll
    for (int ni = 0; ni < 4; ++ni) acc[mi][ni] = (f32x4){0.f, 0.f, 0.f, 0.f};
  gemm256<512>(Ap, Bp, Ab, Bb, wid, lane, acc);
  float bvals[4];
#pragma unroll
  for (int ni = 0; ni < 4; ++ni) bvals[ni] = b1v[nb * 128 + wn * 64 + ni * 16 + lane_lo];
  int colb = nb * 128 + (wn * 16 + lane_lo) * 4;
#pragma unroll
  for (int mi = 0; mi < 4; ++mi)
#pragma unroll
    for (int j = 0; j < 4; ++j) {
      int rl = wm * 64 + mi * 16 + lane_hi * 4 + j;
      u16x4 pk;
#pragma unroll
      for (int ni = 0; ni < 4; ++ni)
        pk[ni] = f2bf(gelu_f(acc[mi][ni][j] + bvals[ni]));
      *(u16x4*)(H + ((size_t)mb * 256 + rl) * 2048 + colb) = pk;
    }
}

// FF2: y = H @ W2 + b2 + X1, bf16 IN-PLACE over X1; dbuf 128^2 core.
__global__ __launch_bounds__(256) void kff2(const u16* __restrict__ H,
                                            const u16* __restrict__ W2T,
                                            const float* __restrict__ b2v,
                                            u16* __restrict__ X1y) {
  __shared__ __align__(16) u16 Ab[16384];
  __shared__ __align__(16) u16 Bb[16384];
  int tid = threadIdx.x, lane = tid & 63, wid = tid >> 6;
  int nwg = gridDim.x, bid = blockIdx.x;
  int m128 = nwg >> 2;
  int xcd = bid & 7, idx = bid >> 3;
  int mb = xcd * (m128 >> 3) + (idx >> 2);
  int nb = idx & 3;
  const u16* Ap = H + (size_t)mb * 128 * 2048;
  const u16* Bp = W2T + (size_t)nb * 128 * 2048;
  f32x4 acc[4][4];
#pragma unroll
  for (int mi = 0; mi < 4; ++mi)
#pragma unroll
    for (int ni = 0; ni < 4; ++ni) acc[mi][ni] = (f32x4){0.f, 0.f, 0.f, 0.f};
  gemm_core_db<2048>(Ap, Bp, Ab, Bb, wid, lane, acc);
  int lane_lo = lane & 15, lane_hi = lane >> 4;
  int wm = wid >> 1, wn = wid & 1;
#pragma unroll
  for (int mi = 0; mi < 4; ++mi)
#pragma unroll
    for (int j = 0; j < 4; ++j) {
      int rl = wm * 64 + mi * 16 + lane_hi * 4 + j;
      size_t row = (size_t)mb * 128 + rl;
      u16* xrow = X1y + row * 512 + nb * 128;
#pragma unroll
      for (int ni = 0; ni < 4; ++ni) {
        int col = wn * 64 + ni * 16 + lane_lo;
        float val = acc[mi][ni][j] + b2v[nb * 128 + col] + bf2f(xrow[col]);
        xrow[col] = f2bf(val);
      }
    }
}

// LN2: out = LN(y) where y is bf16 (in X1 buffer). One wave per row.
__global__ __launch_bounds__(512) void kln2(const u16* __restrict__ Y,
                                            const float* __restrict__ g2,
                                            const float* __restrict__ bb2,
                                            float* __restrict__ out) {
  int wid = threadIdx.x >> 6, lane = threadIdx.x & 63;
  size_t row = (size_t)blockIdx.x * 8 + wid;
  u16x8 v = *(const u16x8*)(Y + row * 512 + lane * 8);
  float f[8];
  float s = 0.f, q = 0.f;
#pragma unroll
  for (int k = 0; k < 8; ++k) {
    f[k] = bf2f(v[k]);
    s += f[k]; q += f[k] * f[k];
  }
#pragma unroll
  for (int off = 1; off < 64; off <<= 1) { s += __shfl_xor(s, off); q += __shfl_xor(q, off); }
  float mu = s * (1.f / 512.f);
  float rs = rsqrtf(q * (1.f / 512.f) - mu * mu + 512.0f);
  float4 ga = *(const float4*)(g2 + lane * 8);
  float4 gb = *(const float4*)(g2 + lane * 8 + 4);
  float4 ba = *(const float4*)(bb2 + lane * 8);
  float4 bb = *(const float4*)(bb2 + lane * 8 + 4);
  float4 o0, o1;
  o0.x = (f[0] - mu) * rs * ga.x + ba.x;
  o0.y = (f[1] - mu) * rs * ga.y + ba.y;
  o0.z = (f[2] - mu) * rs * ga.z + ba.z;
  o0.w = (f[3] - mu) * rs * ga.w + ba.w;
  o1.x = (f[4] - mu) * rs * gb.x + bb.x;
  o1.y = (f[5] - mu) * rs * gb.y + bb.y;
  o1.z = (f[6] - mu) * rs * gb.z + bb.z;
  o1.w = (f[7] - mu) * rs * gb.w + bb.w;
  float* orow = out + row * 512 + lane * 8;
  *(float4*)orow = o0;
  *(float4*)(orow + 4) = o1;
}

extern "C" void kernel_launch(void* const* d_in, const int* in_sizes, int n_in,
                              void* d_out, int out_size, void* d_ws, size_t ws_size,
                              hipStream_t stream) {
  const float* x   = (const float*)d_in[0];
  const float* Wq  = (const float*)d_in[1];
  const float* Wk  = (const float*)d_in[2];
  const float* Wv  = (const float*)d_in[3];
  const float* Wp  = (const float*)d_in[4];
  const float* bp  = (const float*)d_in[5];
  const float* W1  = (const float*)d_in[6];
  const float* b1  = (const float*)d_in[7];
  const float* W2  = (const float*)d_in[8];
  const float* b2  = (const float*)d_in[9];
  const float* g1  = (const float*)d_in[10];
  const float* bb1 = (const float*)d_in[11];
  const float* g2  = (const float*)d_in[12];
  const float* bb2 = (const float*)d_in[13];
  float* out = (float*)d_out;

  char* ws = (char*)d_ws;
  u16* Gbf  = (u16*)ws;                      // 32KB (region reserved 256KB)
  u16* WvpT = (u16*)(ws + (256 << 10));      // 128KB
  u16* W1T  = (u16*)(ws + (1 << 20));        // 2MB
  u16* W2T  = (u16*)(ws + (3 << 20));        // 2MB
  u16* X1   = (u16*)(ws + (21 << 20));       // 64MB (becomes y bf16 after kff2)
  u16* H    = (u16*)(ws + (85ull << 20));    // H slice region

  hipLaunchKernelGGL(kprep_G,   dim3(64),        dim3(256), 0, stream, Wq, Wk, Gbf);
  hipLaunchKernelGGL(kprep_Wvp, dim3(256),       dim3(256), 0, stream, Wv, Wp, WvpT);
  hipLaunchKernelGGL(kprep_W1T, dim3(32, 8),     dim3(256), 0, stream, W1, W1T);
  hipLaunchKernelGGL(kprep_W2T, dim3(32, 8),     dim3(256), 0, stream, W2, W2T);
  hipLaunchKernelGGL(kfused,    dim3(512),       dim3(1024), 0, stream, x, Gbf, WvpT,
                     bp, g1, bb1, X1);

  // S=2 preferred (H slice 128MB L3-resident, fewer launch tails); fallback smaller.
  const size_t hbase = 85ull << 20;
  int S = 64;
  for (int c = 2; c <= 64; c <<= 1) {
    if (hbase + (268435456ull / (size_t)c) <= ws_size) { S = c; break; }
  }
  int Ms = MROWS / S;
  for (int s = 0; s < S; ++s) {
    const u16* x1s = X1 + (size_t)s * Ms * 512;
    hipLaunchKernelGGL(kff1, dim3((Ms / 256) * 16), dim3(512), 0, stream, x1s, W1T, b1, H);
    hipLaunchKernelGGL(kff2, dim3((Ms / 128) * 4),  dim3(256), 0, stream, H, W2T, b2,
                       X1 + (size_t)s * Ms * 512);
  }
  hipLaunchKernelGGL(kln2, dim3(8192), dim3(512), 0, stream, X1, g2, bb2, out);
}